// Round 1
// baseline (337.270 us; speedup 1.0000x reference)
//
#include <hip/hip_runtime.h>
#include <hip/hip_cooperative_groups.h>

namespace cg = cooperative_groups;

// Problem constants: B=4, S=2048, D=1024, G=256, I=1024, H=16
#define BB 4
#define SS 2048
#define DD 1024
#define II 1024

// Algebraic collapse (verified rounds 1-4): keys identical across seq ->
// softmax uniform -> out[b,s,:] = ((mean_s x[b,s,:]) @ Wv) @ Wo broadcast
// over s. Wq/Wk/structure_features unused.
//
// Round 6: the 5-kernel pipeline's work is ~14.5 us but dur_us carries
// ~14 us of inter-dispatch overhead (4 dependent launch gaps + drain).
// Fuse everything into ONE cooperative kernel with grid.sync() between
// stages; stage shapes match the proven per-kernel shapes.
//   A (512 blk): x -> pbuf[512][1024]            (~5.3 us, BW)
//   B ( 64 blk): pbuf -> xbar = mean_s x         (~0.5 us)
//   C ( 64 blk): tvec = xbar @ Wv                (~1.5 us)
//   D ( 64 blk): orow = tvec @ Wo                (~1.5 us)
//   E (512 blk): broadcast orow -> out           (~5.3 us, BW)

constexpr int NBLK  = 512;          // cooperative grid: 2 blocks/CU
constexpr int JP    = 128;          // partials per batch (NBLK/BB)
constexpr int ROWS1 = SS / JP;      // 16 rows summed per block in stage A
constexpr int REDLD = 65;           // padded LDS reduction stride (bank-friendly)

typedef float f4 __attribute__((ext_vector_type(4)));

// GEMV: outv[b][i0:i0+16] = vec[b][:] @ W  for all 4 b.  256 threads:
// il = col 0..15, ks = k-group 0..15 (64 k each). Wave = 4 ks x 16 il ->
// four 64B segments per W load (coalesced sectors). LDS tree-reduce.
__device__ __forceinline__
void gemv16(const float* __restrict__ vec, const float* __restrict__ W,
            float* __restrict__ outv, int g, int tid,
            float* __restrict__ xs, float* __restrict__ red)
{
    #pragma unroll
    for (int r = 0; r < 4; ++r)
        ((f4*)xs)[tid + 256 * r] = ((const f4*)vec)[tid + 256 * r];
    __syncthreads();

    const int i0 = g * 16;
    const int il = tid & 15, ks = tid >> 4;
    const float* wp = W + (size_t)(ks * 64) * DD + i0 + il;
    float a0 = 0.f, a1 = 0.f, a2 = 0.f, a3 = 0.f;
    #pragma unroll 16
    for (int kk = 0; kk < 64; ++kk) {
        const float w = wp[(size_t)kk * DD];
        const int k = ks * 64 + kk;
        a0 += xs[0 * DD + k] * w;
        a1 += xs[1 * DD + k] * w;
        a2 += xs[2 * DD + k] * w;
        a3 += xs[3 * DD + k] * w;
    }
    red[ks * REDLD +  0 + il] = a0;
    red[ks * REDLD + 16 + il] = a1;
    red[ks * REDLD + 32 + il] = a2;
    red[ks * REDLD + 48 + il] = a3;
    __syncthreads();
    if (tid < 64) {
        float s = 0.f;
        #pragma unroll
        for (int q = 0; q < 16; ++q) s += red[q * REDLD + tid];
        const int b = tid >> 4, i = tid & 15;
        outv[b * DD + i0 + i] = s;
    }
    __syncthreads();   // xs/red safe for reuse once block re-converges
}

__global__ __launch_bounds__(256, 2)
void fused_all(const float* __restrict__ x,
               const float* __restrict__ Wv,
               const float* __restrict__ Wo,
               float* __restrict__ pbuf,
               float* __restrict__ xbar,
               float* __restrict__ tvec,
               float* __restrict__ orow,
               float* __restrict__ out)
{
    __shared__ float xs[BB * DD];           // 16 KB (stage B reuses as f4[256])
    __shared__ float red[16 * REDLD];       // ~4.1 KB

    cg::grid_group grid = cg::this_grid();
    const int g   = blockIdx.x;
    const int tid = threadIdx.x;

    // ---- Stage A: 512 blocks, each sums 16 consecutive rows of x -> pbuf[g]
    {
        const f4* xr = (const f4*)x + (size_t)g * ROWS1 * (DD / 4) + tid;
        f4 a = (f4)(0.f);
        #pragma unroll
        for (int r = 0; r < ROWS1; ++r)
            a += __builtin_nontemporal_load(xr + (size_t)r * (DD / 4));
        ((f4*)pbuf)[(size_t)g * (DD / 4) + tid] = a;
    }
    grid.sync();

    // ---- Stage B: blocks 0..63 reduce pbuf -> xbar (scaled 1/S)
    if (g < 64) {
        const int b = g >> 4, dg = g & 15;
        const int c4 = tid & 15;             // float4 column within 64-col slice
        const int jg = tid >> 4;             // 16 j-groups of 8
        const f4* p = (const f4*)pbuf + ((size_t)b * JP + jg * 8) * (DD / 4)
                      + dg * 16 + c4;
        f4 a = (f4)(0.f);
        #pragma unroll
        for (int j = 0; j < 8; ++j)
            a += p[(size_t)j * (DD / 4)];
        f4* redb = (f4*)xs;                  // 16x16 f4 = 4 KB
        redb[jg * 16 + c4] = a;
        __syncthreads();
        if (tid < 16) {
            f4 s = (f4)(0.f);
            #pragma unroll
            for (int q = 0; q < 16; ++q) s += redb[q * 16 + tid];
            ((f4*)xbar)[b * (DD / 4) + dg * 16 + tid] = s * (1.0f / (float)SS);
        }
    }
    grid.sync();

    // ---- Stage C: tvec = xbar @ Wv   (blocks 0..63)
    if (g < 64) gemv16(xbar, Wv, tvec, g, tid, xs, red);
    grid.sync();

    // ---- Stage D: orow = tvec @ Wo   (blocks 0..63)
    if (g < 64) gemv16(tvec, Wo, orow, g, tid, xs, red);
    grid.sync();

    // ---- Stage E: broadcast orow -> out, 16 rows per block
    {
        const int b  = g >> 7;
        const int s0 = (g & 127) * 16;
        const f4 c = ((const f4*)orow)[b * (DD / 4) + tid];
        f4* o = (f4*)out + (size_t)(b * SS + s0) * (DD / 4) + tid;
        #pragma unroll
        for (int r = 0; r < 16; ++r)
            __builtin_nontemporal_store(c, o + (size_t)r * (DD / 4));
    }
}

// ---------------- Fallback: proven 5-kernel pipeline (round 5) -------------

__global__ __launch_bounds__(256)
void k1_partial(const float4* __restrict__ x, float4* __restrict__ pbuf) {
    const int g = blockIdx.x;
    const float4* xr = x + (size_t)g * ROWS1 * (DD / 4) + threadIdx.x;
    float4 a = make_float4(0.f, 0.f, 0.f, 0.f);
    #pragma unroll
    for (int r = 0; r < ROWS1; ++r) {
        float4 v = xr[(size_t)r * (DD / 4)];
        a.x += v.x; a.y += v.y; a.z += v.z; a.w += v.w;
    }
    pbuf[(size_t)g * (DD / 4) + threadIdx.x] = a;
}

__global__ __launch_bounds__(256)
void kred(const float4* __restrict__ pbuf, float4* __restrict__ xbar) {
    const int b = blockIdx.x >> 4, dg = blockIdx.x & 15;
    const int c4 = threadIdx.x & 15;
    const int jg = threadIdx.x >> 4;
    const float4* p = pbuf + ((size_t)b * JP + jg * 8) * (DD / 4) + dg * 16 + c4;
    float4 a = make_float4(0.f, 0.f, 0.f, 0.f);
    #pragma unroll
    for (int j = 0; j < 8; ++j) {
        float4 v = p[(size_t)j * (DD / 4)];
        a.x += v.x; a.y += v.y; a.z += v.z; a.w += v.w;
    }
    __shared__ float4 red2[16][16];
    red2[jg][c4] = a;
    __syncthreads();
    if (threadIdx.x < 16) {
        float4 s = make_float4(0.f, 0.f, 0.f, 0.f);
        #pragma unroll
        for (int q = 0; q < 16; ++q) {
            float4 v = red2[q][threadIdx.x];
            s.x += v.x; s.y += v.y; s.z += v.z; s.w += v.w;
        }
        const float sc = 1.0f / (float)SS;
        xbar[b * (DD / 4) + dg * 16 + threadIdx.x] =
            make_float4(s.x * sc, s.y * sc, s.z * sc, s.w * sc);
    }
}

__global__ __launch_bounds__(1024)
void kg_gemv(const float4* __restrict__ vec, const float* __restrict__ W,
             float* __restrict__ out) {
    __shared__ float xs[BB * DD];
    const int tid = threadIdx.x;
    ((float4*)xs)[tid] = vec[tid];
    __syncthreads();

    const int i0 = blockIdx.x * 16;
    const int il = tid & 15, ks = tid >> 4;
    float a0 = 0.f, a1 = 0.f, a2 = 0.f, a3 = 0.f;
    #pragma unroll
    for (int kk = 0; kk < 16; ++kk) {
        const int k = ks * 16 + kk;
        const float w = W[(size_t)k * DD + i0 + il];
        a0 += xs[0 * DD + k] * w;
        a1 += xs[1 * DD + k] * w;
        a2 += xs[2 * DD + k] * w;
        a3 += xs[3 * DD + k] * w;
    }

    __shared__ float red3[64 * 64];
    red3[ks * 64 +  0 + il] = a0;
    red3[ks * 64 + 16 + il] = a1;
    red3[ks * 64 + 32 + il] = a2;
    red3[ks * 64 + 48 + il] = a3;
    __syncthreads();
    if (tid < 64) {
        float s = 0.f;
        #pragma unroll
        for (int q = 0; q < 64; ++q) s += red3[q * 64 + tid];
        const int b = tid >> 4, i = tid & 15;
        out[b * DD + i0 + i] = s;
    }
}

__global__ __launch_bounds__(256)
void k4_bcast(const float4* __restrict__ orow, float4* __restrict__ out) {
    const int g = blockIdx.x;
    const int b = g >> 9;
    const int s0 = (g & 511) * 4;
    const float4 c = orow[b * (DD / 4) + threadIdx.x];
    float4* o = out + (size_t)(b * SS + s0) * (DD / 4) + threadIdx.x;
    #pragma unroll
    for (int r = 0; r < 4; ++r) o[(size_t)r * (DD / 4)] = c;
}

extern "C" void kernel_launch(void* const* d_in, const int* in_sizes, int n_in,
                              void* d_out, int out_size, void* d_ws, size_t ws_size,
                              hipStream_t stream) {
    const float* x  = (const float*)d_in[0];  // inputs_embeds [B,S,D]
    const float* Wv = (const float*)d_in[4];  // [D,I]
    const float* Wo = (const float*)d_in[5];  // [I,D]
    float* out = (float*)d_out;

    float* pbuf = (float*)d_ws;                       // NBLK*DD floats (2 MB)
    float* xbar = pbuf + (size_t)NBLK * DD;           // [4][1024]
    float* tvec = xbar + (size_t)BB * DD;             // [4][1024]
    float* orow = tvec + (size_t)BB * II;             // [4][1024]

    void* args[] = { (void*)&x, (void*)&Wv, (void*)&Wo,
                     (void*)&pbuf, (void*)&xbar, (void*)&tvec, (void*)&orow,
                     (void*)&out };
    hipError_t err = hipLaunchCooperativeKernel(
        reinterpret_cast<void*>(fused_all), dim3(NBLK), dim3(256),
        args, 0, stream);

    if (err != hipSuccess) {
        // Fallback: the proven round-5 pipeline (neutral, never worse).
        k1_partial<<<BB * JP, 256, 0, stream>>>((const float4*)x, (float4*)pbuf);
        kred<<<64, 256, 0, stream>>>((const float4*)pbuf, (float4*)xbar);
        kg_gemv<<<II / 16, 1024, 0, stream>>>((const float4*)xbar, Wv, tvec);
        kg_gemv<<<DD / 16, 1024, 0, stream>>>((const float4*)tvec, Wo, orow);
        k4_bcast<<<(BB * SS) / 4, 256, 0, stream>>>((const float4*)orow, (float4*)out);
    }
}

// Round 2
// 109.365 us; speedup vs baseline: 3.0839x; 3.0839x over previous
//
#include <hip/hip_runtime.h>

// Problem constants: B=4, S=2048, D=1024, G=256, I=1024, H=16
#define BB 4
#define SS 2048
#define DD 1024
#define II 1024

// Algebraic collapse (verified rounds 1-4): keys identical across seq ->
// softmax uniform -> out[b,s,:] = ((mean_s x[b,s,:]) @ Wv) @ Wo broadcast
// over s. Wq/Wk/structure_features unused.
//
// Round 6 post-mortem: cooperative grid.sync costs ~55 us/sync on gfx950
// (cross-XCD coherence: acq_rel atomics + L2 wb/inv per arrival) -> fused
// single-kernel was 2.1x SLOWER. Reverted to the proven 5-kernel pipeline.
//
// Round 7: widen the GEMVs (64 -> 256 blocks via batch-split; GEMV was
// CU-count-limited at 42 GB/s/CU) and use nontemporal stores in k4.
//   k1   ( 512 blk x  256): x -> pbuf[4][128][1024]          (~5.5 us, BW)
//   kred (  64 blk x  256): pbuf -> xbar  (b x 16 col-groups) (~0.5 us)
//   kg   ( 256 blk x 1024): per-(b, 16-col) GEMV              (~0.9 us each)
//   k4   (2048 blk x  256): broadcast orow -> out             (~5.1 us, BW)

constexpr int JP = 128;            // partials per batch
constexpr int ROWS1 = SS / JP;     // 16 rows per k1 block

typedef float f4 __attribute__((ext_vector_type(4)));

// k1: pbuf[g][:] = sum of 16 consecutive rows of x  (g = b*128 + j)
__global__ __launch_bounds__(256)
void k1_partial(const float4* __restrict__ x, float4* __restrict__ pbuf) {
    const int g = blockIdx.x;                 // 512 blocks
    const float4* xr = x + (size_t)g * ROWS1 * (DD / 4) + threadIdx.x;
    float4 a = make_float4(0.f, 0.f, 0.f, 0.f);
    #pragma unroll
    for (int r = 0; r < ROWS1; ++r) {
        float4 v = xr[(size_t)r * (DD / 4)];
        a.x += v.x; a.y += v.y; a.z += v.z; a.w += v.w;
    }
    pbuf[(size_t)g * (DD / 4) + threadIdx.x] = a;
}

// kred: xbar[b][dg*64 : +64] = (1/S) * sum_j pbuf[b][j][slice]
// 64 blocks = (b, dg); thread = (jg 0..15, c4 0..15); each sums 8 j's.
__global__ __launch_bounds__(256)
void kred(const float4* __restrict__ pbuf, float4* __restrict__ xbar) {
    const int b = blockIdx.x >> 4, dg = blockIdx.x & 15;
    const int c4 = threadIdx.x & 15;          // float4 column within slice
    const int jg = threadIdx.x >> 4;          // 16 j-groups of 8
    const float4* p = pbuf + ((size_t)b * JP + jg * 8) * (DD / 4) + dg * 16 + c4;
    float4 a = make_float4(0.f, 0.f, 0.f, 0.f);
    #pragma unroll
    for (int j = 0; j < 8; ++j) {
        float4 v = p[(size_t)j * (DD / 4)];
        a.x += v.x; a.y += v.y; a.z += v.z; a.w += v.w;
    }
    __shared__ float4 red[16][16];            // 4 KB
    red[jg][c4] = a;
    __syncthreads();
    if (threadIdx.x < 16) {
        float4 s = make_float4(0.f, 0.f, 0.f, 0.f);
        #pragma unroll
        for (int q = 0; q < 16; ++q) {
            float4 v = red[q][threadIdx.x];
            s.x += v.x; s.y += v.y; s.z += v.z; s.w += v.w;
        }
        const float sc = 1.0f / (float)SS;
        xbar[b * (DD / 4) + dg * 16 + threadIdx.x] =
            make_float4(s.x * sc, s.y * sc, s.z * sc, s.w * sc);
    }
}

// kg: out[b][i0:i0+16] = vec[b][:] @ W   (vec: [4][1024], W: [1024][1024])
// 256 blocks = (b 0..3) x (cg 0..63); 1024 threads = (ks 0..63) x (il 0..15).
// Engages all 256 CUs (the 64-block version was CU-count-limited at
// ~42 GB/s/CU); 4x redundant W reads are L2/L3-absorbed (16 MB total).
__global__ __launch_bounds__(1024)
void kg_gemv_b(const float4* __restrict__ vec, const float* __restrict__ W,
               float* __restrict__ out) {
    __shared__ float xs[DD];                  // this block's batch row, 4 KB
    const int cg = blockIdx.x & 63;
    const int b  = blockIdx.x >> 6;
    const int tid = threadIdx.x;
    if (tid < DD / 4) ((f4*)xs)[tid] = ((const f4*)vec)[b * (DD / 4) + tid];
    __syncthreads();

    const int i0 = cg * 16;
    const int il = tid & 15, ks = tid >> 4;   // 64 k-groups of 16
    const float* wp = W + (size_t)(ks * 16) * DD + i0 + il;
    float a = 0.f;
    #pragma unroll
    for (int kk = 0; kk < 16; ++kk)
        a += xs[ks * 16 + kk] * wp[(size_t)kk * DD];

    __shared__ float red[64 * 16];            // [ks][il], 4 KB
    __shared__ float red2[4 * 16];
    red[ks * 16 + il] = a;
    __syncthreads();
    // 2-stage reduce (the 64-deep serial loop costs ~400 serial cycles)
    if (tid < 64) {                           // q = tid>>4 (0..3), il = tid&15
        const int q = tid >> 4, i = tid & 15;
        float s = 0.f;
        #pragma unroll
        for (int k = 0; k < 16; ++k) s += red[(q * 16 + k) * 16 + i];
        red2[q * 16 + i] = s;
    }
    __syncthreads();
    if (tid < 16) {
        float s = red2[0 * 16 + tid] + red2[1 * 16 + tid]
                + red2[2 * 16 + tid] + red2[3 * 16 + tid];
        out[b * DD + i0 + tid] = s;
    }
}

// k4: out[b][s][:] = orow[b][:], 4 rows per block, nontemporal float4 stores
__global__ __launch_bounds__(256)
void k4_bcast(const f4* __restrict__ orow, f4* __restrict__ out) {
    const int g = blockIdx.x;                 // 2048 blocks
    const int b = g >> 9;
    const int s0 = (g & 511) * 4;
    const f4 c = orow[b * (DD / 4) + threadIdx.x];
    f4* o = out + (size_t)(b * SS + s0) * (DD / 4) + threadIdx.x;
    #pragma unroll
    for (int r = 0; r < 4; ++r)
        __builtin_nontemporal_store(c, o + (size_t)r * (DD / 4));
}

extern "C" void kernel_launch(void* const* d_in, const int* in_sizes, int n_in,
                              void* d_out, int out_size, void* d_ws, size_t ws_size,
                              hipStream_t stream) {
    const float* x  = (const float*)d_in[0];  // inputs_embeds [B,S,D]
    const float* Wv = (const float*)d_in[4];  // [D,I]
    const float* Wo = (const float*)d_in[5];  // [I,D]
    float* out = (float*)d_out;

    float* pbuf = (float*)d_ws;                       // BB*JP*DD floats (2 MB)
    float* xbar = pbuf + (size_t)BB * JP * DD;        // [4][1024]
    float* tvec = xbar + (size_t)BB * DD;             // [4][1024]
    float* orow = tvec + (size_t)BB * II;             // [4][1024]

    k1_partial<<<BB * JP, 256, 0, stream>>>((const float4*)x, (float4*)pbuf);
    kred<<<64, 256, 0, stream>>>((const float4*)pbuf, (float4*)xbar);
    kg_gemv_b<<<256, 1024, 0, stream>>>((const float4*)xbar, Wv, tvec);
    kg_gemv_b<<<256, 1024, 0, stream>>>((const float4*)tvec, Wo, orow);
    k4_bcast<<<(BB * SS) / 4, 256, 0, stream>>>((const f4*)orow, (f4*)out);
}